// Round 1
// baseline (249.382 us; speedup 1.0000x reference)
//
#include <hip/hip_runtime.h>

// RGCN layer, basis decomposition.
//   Hb[n][b][o] = sum_i h[n][i] * weight[b][i][o]          (stage 1, dense)
//   msg[e][o]   = norm[e] * sum_b w_comp[etype[e]][b] * Hb[src[e]][b][o]
//   out[n][o]   = relu( sum_{e: dst[e]==n} msg[e][o] + bias[o] )
//
// IN = OUT = 64, B = 4, R = 32 are compile-time; N, E taken from in_sizes.

constexpr int BASES = 4;

// ---------------- Stage 1: Hb = h @ weight (per basis) ----------------
// Block = 256 threads. Thread t owns (b = t>>6, o = t&63) and keeps
// weight[b][:, o] (64 f32) in registers for the whole kernel. 16 h-rows
// are staged in LDS per iteration; each thread does 16x64 FMAs.
__global__ __launch_bounds__(256) void hb_kernel(const float* __restrict__ h,
                                                 const float* __restrict__ weight,
                                                 float* __restrict__ Hb, int N) {
    __shared__ float sh[16][64];
    const int t = threadIdx.x;
    const int b = t >> 6;
    const int o = t & 63;

    float wcol[64];
#pragma unroll
    for (int i = 0; i < 64; ++i)
        wcol[i] = weight[b * 4096 + i * 64 + o];   // lanes: consecutive o -> coalesced

    for (int node0 = blockIdx.x * 16; node0 < N; node0 += gridDim.x * 16) {
        __syncthreads();
#pragma unroll
        for (int p = 0; p < 4; ++p) {
            int idx = p * 256 + t;
            int r = idx >> 6, c = idx & 63;
            int node = node0 + r;
            sh[r][c] = (node < N) ? h[(size_t)node * 64 + c] : 0.f;
        }
        __syncthreads();
        int rmax = (N - node0 < 16) ? (N - node0) : 16;
        for (int r = 0; r < rmax; ++r) {
            float acc = 0.f;
#pragma unroll
            for (int i = 0; i < 64; ++i)
                acc += sh[r][i] * wcol[i];          // sh read is wave-uniform broadcast
            Hb[(size_t)(node0 + r) * 256 + t] = acc; // 256 consecutive floats -> coalesced
        }
    }
}

// ---------------- Stage 2: per-edge message + atomic scatter ----------------
// One wave processes a contiguous chunk of edges; lane = output column.
__global__ __launch_bounds__(256) void edge_kernel(const float* __restrict__ Hb,
                                                   const float* __restrict__ w_comp,
                                                   const float* __restrict__ edge_norm,
                                                   const int* __restrict__ src,
                                                   const int* __restrict__ dst,
                                                   const int* __restrict__ etype,
                                                   float* __restrict__ out, int E) {
    const int lane = threadIdx.x & 63;
    const int gwave = (blockIdx.x * blockDim.x + threadIdx.x) >> 6;
    const int nwaves = (gridDim.x * blockDim.x) >> 6;
    const int chunk = (E + nwaves - 1) / nwaves;
    const int e0 = gwave * chunk;
    const int e1 = (e0 + chunk < E) ? (e0 + chunk) : E;

    for (int e = e0; e < e1; ++e) {
        int s = src[e];
        int d = dst[e];
        int r = etype[e];
        float nm = edge_norm[e];
        const float* hb = Hb + (size_t)s * 256;
        const float* cf = w_comp + r * 4;
        float v = cf[0] * hb[lane]
                + cf[1] * hb[64 + lane]
                + cf[2] * hb[128 + lane]
                + cf[3] * hb[192 + lane];
        atomicAdd(&out[(size_t)d * 64 + lane], v * nm);
    }
}

// ---------------- Fallback (ws too small): direct per-edge compute ----------------
__global__ __launch_bounds__(256) void edge_direct_kernel(const float* __restrict__ h,
                                                          const float* __restrict__ weight,
                                                          const float* __restrict__ w_comp,
                                                          const float* __restrict__ edge_norm,
                                                          const int* __restrict__ src,
                                                          const int* __restrict__ dst,
                                                          const int* __restrict__ etype,
                                                          float* __restrict__ out, int E) {
    const int lane = threadIdx.x & 63;
    const int gwave = (blockIdx.x * blockDim.x + threadIdx.x) >> 6;
    const int nwaves = (gridDim.x * blockDim.x) >> 6;
    const int chunk = (E + nwaves - 1) / nwaves;
    const int e0 = gwave * chunk;
    const int e1 = (e0 + chunk < E) ? (e0 + chunk) : E;

    for (int e = e0; e < e1; ++e) {
        int s = src[e];
        int d = dst[e];
        int r = etype[e];
        float nm = edge_norm[e];
        const float* cf = w_comp + r * 4;
        float c0 = cf[0], c1 = cf[1], c2 = cf[2], c3 = cf[3];
        float acc = 0.f;
        const float* hrow = h + (size_t)s * 64;
#pragma unroll 8
        for (int i = 0; i < 64; ++i) {
            float hv = hrow[i];
            float w = c0 * weight[0 * 4096 + i * 64 + lane]
                    + c1 * weight[1 * 4096 + i * 64 + lane]
                    + c2 * weight[2 * 4096 + i * 64 + lane]
                    + c3 * weight[3 * 4096 + i * 64 + lane];
            acc += hv * w;
        }
        atomicAdd(&out[(size_t)d * 64 + lane], acc * nm);
    }
}

// ---------------- Stage 3: bias + relu (in place on out) ----------------
__global__ __launch_bounds__(256) void bias_relu_kernel(float* __restrict__ out,
                                                        const float* __restrict__ bias,
                                                        int total) {
    int i = blockIdx.x * blockDim.x + threadIdx.x;
    int stride = gridDim.x * blockDim.x;
    for (; i < total; i += stride) {
        float v = out[i] + bias[i & 63];
        out[i] = v > 0.f ? v : 0.f;
    }
}

extern "C" void kernel_launch(void* const* d_in, const int* in_sizes, int n_in,
                              void* d_out, int out_size, void* d_ws, size_t ws_size,
                              hipStream_t stream) {
    const float* h         = (const float*)d_in[0];
    const float* weight    = (const float*)d_in[1];
    const float* w_comp    = (const float*)d_in[2];
    const float* bias      = (const float*)d_in[3];
    const float* edge_norm = (const float*)d_in[4];
    const int*   src       = (const int*)d_in[5];
    const int*   dst       = (const int*)d_in[6];
    const int*   etype     = (const int*)d_in[7];
    float* out = (float*)d_out;

    const int N = in_sizes[0] / 64;
    const int E = in_sizes[4];

    // zero the accumulator (d_out is poisoned, and replays must be self-contained)
    hipMemsetAsync(d_out, 0, (size_t)N * 64 * sizeof(float), stream);

    const size_t hb_bytes = (size_t)N * (BASES * 64) * sizeof(float);
    if (ws_size >= hb_bytes) {
        float* Hb = (float*)d_ws;
        hb_kernel<<<1024, 256, 0, stream>>>(h, weight, Hb, N);
        edge_kernel<<<2048, 256, 0, stream>>>(Hb, w_comp, edge_norm, src, dst, etype, out, E);
    } else {
        edge_direct_kernel<<<2048, 256, 0, stream>>>(h, weight, w_comp, edge_norm, src, dst,
                                                     etype, out, E);
    }
    bias_relu_kernel<<<2048, 256, 0, stream>>>(out, bias, N * 64);
}

// Round 2
// 240.492 us; speedup vs baseline: 1.0370x; 1.0370x over previous
//
#include <hip/hip_runtime.h>

// RGCN layer, basis decomposition — CSR-reordered formulation.
//
//   G[n][b][i] = sum_{e: dst[e]==n} (norm_e * w_comp[etype_e][b]) * h[src_e][i]
//   out[n][o]  = relu( sum_b sum_i G[n][b][i] * weight[b][i][o] + bias[o] )
//
// Pipeline: hist(dst) -> scan -> fill(sorted edge records) -> aggregate (no
// atomics on float data) -> dense transform GEMM (fused bias+relu).
// Fallback to the round-1 Hb+atomic path if ws_size is too small.

constexpr int BASES = 4;

// ============================ CSR build ============================

__global__ __launch_bounds__(256) void hist_kernel(const int* __restrict__ dst,
                                                   int* __restrict__ counts, int E) {
    int i = blockIdx.x * blockDim.x + threadIdx.x;
    int st = gridDim.x * blockDim.x;
    for (; i < E; i += st) atomicAdd(&counts[dst[i]], 1);
}

// per-block sums of 256 counts
__global__ __launch_bounds__(256) void scan1_kernel(const int* __restrict__ counts,
                                                    int* __restrict__ bsum, int N) {
    __shared__ int s[256];
    int t = threadIdx.x;
    int i = blockIdx.x * 256 + t;
    s[t] = (i < N) ? counts[i] : 0;
    __syncthreads();
    for (int off = 128; off > 0; off >>= 1) {
        if (t < off) s[t] += s[t + off];
        __syncthreads();
    }
    if (t == 0) bsum[blockIdx.x] = s[0];
}

// exclusive scan of block sums (nb <= 256); also writes offsets[N] = E
__global__ __launch_bounds__(256) void scan2_kernel(int* __restrict__ bsum, int nb,
                                                    int* __restrict__ offsets, int N, int E) {
    __shared__ int s[256];
    int t = threadIdx.x;
    int v = (t < nb) ? bsum[t] : 0;
    s[t] = v;
    __syncthreads();
    for (int off = 1; off < 256; off <<= 1) {
        int x = (t >= off) ? s[t - off] : 0;
        __syncthreads();
        s[t] += x;
        __syncthreads();
    }
    if (t < nb) bsum[t] = s[t] - v;   // exclusive
    if (t == 0) offsets[N] = E;
}

// per-block exclusive scan + block offset -> offsets & cursor copy
__global__ __launch_bounds__(256) void scan3_kernel(const int* __restrict__ counts,
                                                    const int* __restrict__ bsum,
                                                    int* __restrict__ offsets,
                                                    int* __restrict__ cursor, int N) {
    __shared__ int s[256];
    int t = threadIdx.x;
    int i = blockIdx.x * 256 + t;
    int v = (i < N) ? counts[i] : 0;
    s[t] = v;
    __syncthreads();
    for (int off = 1; off < 256; off <<= 1) {
        int x = (t >= off) ? s[t - off] : 0;
        __syncthreads();
        s[t] += x;
        __syncthreads();
    }
    if (i < N) {
        int ex = s[t] - v + bsum[blockIdx.x];
        offsets[i] = ex;
        cursor[i] = ex;
    }
}

// scatter edges into dst-sorted order as packed 16B records {src, etype, norm, pad}
__global__ __launch_bounds__(256) void fill_kernel(const int* __restrict__ src,
                                                   const int* __restrict__ dst,
                                                   const int* __restrict__ etype,
                                                   const float* __restrict__ norm,
                                                   int* __restrict__ cursor,
                                                   uint4* __restrict__ packed, int E) {
    int i = blockIdx.x * blockDim.x + threadIdx.x;
    int st = gridDim.x * blockDim.x;
    for (; i < E; i += st) {
        int d = dst[i];
        int pos = atomicAdd(&cursor[d], 1);
        uint4 r;
        r.x = (unsigned)src[i];
        r.y = (unsigned)etype[i];
        r.z = __float_as_uint(norm[i]);
        r.w = 0u;
        packed[pos] = r;
    }
}

// ============================ Aggregation ============================
// One wave per node (lane = feature i). G accumulated in 4 VGPRs, no atomics.
__global__ __launch_bounds__(256) void agg_kernel(const uint4* __restrict__ packed,
                                                  const int* __restrict__ offsets,
                                                  const float* __restrict__ h,
                                                  const float4* __restrict__ wc4,
                                                  float* __restrict__ G, int N) {
    const int lane = threadIdx.x & 63;
    int wave = (blockIdx.x * blockDim.x + threadIdx.x) >> 6;
    int nw = (gridDim.x * blockDim.x) >> 6;
    for (int n = wave; n < N; n += nw) {
        int e0 = offsets[n], e1 = offsets[n + 1];
        float g0 = 0.f, g1 = 0.f, g2 = 0.f, g3 = 0.f;
        for (int e = e0; e < e1; ++e) {
            uint4 rec = packed[e];                         // wave-uniform broadcast
            float hv = h[(size_t)rec.x * 64 + lane];       // 256B coalesced gather
            float4 c = wc4[rec.y];                         // 512B table, L1-hit
            float nm = __uint_as_float(rec.z);
            g0 = fmaf(c.x * nm, hv, g0);
            g1 = fmaf(c.y * nm, hv, g1);
            g2 = fmaf(c.z * nm, hv, g2);
            g3 = fmaf(c.w * nm, hv, g3);
        }
        float* gp = G + (size_t)n * 256;
        gp[lane] = g0;
        gp[64 + lane] = g1;
        gp[128 + lane] = g2;
        gp[192 + lane] = g3;
    }
}

// ============================ Transform GEMM ============================
// out[n][o] = relu(bias[o] + sum_b sum_i G[n][b][i]*weight[b][i][o])
// Thread t: b = t>>6, o = t&63; weight column in 64 VGPRs. 16-node tiles
// staged through LDS; 4-way basis partials reduced via a second LDS buffer.
__global__ __launch_bounds__(256) void transform_kernel(const float* __restrict__ G,
                                                        const float* __restrict__ weight,
                                                        const float* __restrict__ bias,
                                                        float* __restrict__ out, int N) {
    __shared__ float sh[16 * 256];
    __shared__ float sp[16 * 256];
    const int t = threadIdx.x;
    const int b = t >> 6, o = t & 63;

    float wcol[64];
#pragma unroll
    for (int i = 0; i < 64; ++i) wcol[i] = weight[b * 4096 + i * 64 + o];
    const float bo = bias[o];

    const int ntiles = (N + 15) / 16;
    for (int tile = blockIdx.x; tile < ntiles; tile += gridDim.x) {
        const int n0 = tile * 16;
#pragma unroll
        for (int p = 0; p < 4; ++p) {                   // load 16x256 floats as float4
            int idx = p * 256 + t;                      // 0..1023 float4 slots
            int row = idx >> 6, col = idx & 63;
            int n = n0 + row;
            float4 v = (n < N) ? ((const float4*)G)[(size_t)n * 64 + col]
                               : make_float4(0.f, 0.f, 0.f, 0.f);
            ((float4*)sh)[idx] = v;
        }
        __syncthreads();
        for (int r = 0; r < 16; ++r) {
            const float* g = &sh[r * 256 + b * 64];     // wave-uniform -> broadcast
            float acc = 0.f;
#pragma unroll
            for (int i = 0; i < 64; i += 4) {
                float4 gv = *(const float4*)&g[i];
                acc = fmaf(gv.x, wcol[i], acc);
                acc = fmaf(gv.y, wcol[i + 1], acc);
                acc = fmaf(gv.z, wcol[i + 2], acc);
                acc = fmaf(gv.w, wcol[i + 3], acc);
            }
            sp[r * 256 + b * 64 + o] = acc;
        }
        __syncthreads();
#pragma unroll
        for (int p = 0; p < 4; ++p) {                   // reduce 4 basis partials
            int j = p * 256 + t;
            int r = j >> 6, oo = j & 63;
            int n = n0 + r;
            if (n < N) {
                float v = sp[r * 256 + oo] + sp[r * 256 + 64 + oo] +
                          sp[r * 256 + 128 + oo] + sp[r * 256 + 192 + oo] + bo;
                out[(size_t)n * 64 + oo] = v > 0.f ? v : 0.f;
            }
        }
        __syncthreads();
    }
}

// ============================ Fallback path (round-1) ============================

__global__ __launch_bounds__(256) void hb_kernel(const float* __restrict__ h,
                                                 const float* __restrict__ weight,
                                                 float* __restrict__ Hb, int N) {
    __shared__ float sh[16][64];
    const int t = threadIdx.x;
    const int b = t >> 6;
    const int o = t & 63;
    float wcol[64];
#pragma unroll
    for (int i = 0; i < 64; ++i) wcol[i] = weight[b * 4096 + i * 64 + o];
    for (int node0 = blockIdx.x * 16; node0 < N; node0 += gridDim.x * 16) {
        __syncthreads();
#pragma unroll
        for (int p = 0; p < 4; ++p) {
            int idx = p * 256 + t;
            int r = idx >> 6, c = idx & 63;
            int node = node0 + r;
            sh[r][c] = (node < N) ? h[(size_t)node * 64 + c] : 0.f;
        }
        __syncthreads();
        int rmax = (N - node0 < 16) ? (N - node0) : 16;
        for (int r = 0; r < rmax; ++r) {
            float acc = 0.f;
#pragma unroll
            for (int i = 0; i < 64; ++i) acc += sh[r][i] * wcol[i];
            Hb[(size_t)(node0 + r) * 256 + t] = acc;
        }
    }
}

__global__ __launch_bounds__(256) void edge_kernel(const float* __restrict__ Hb,
                                                   const float* __restrict__ w_comp,
                                                   const float* __restrict__ edge_norm,
                                                   const int* __restrict__ src,
                                                   const int* __restrict__ dst,
                                                   const int* __restrict__ etype,
                                                   float* __restrict__ out, int E) {
    const int lane = threadIdx.x & 63;
    const int gwave = (blockIdx.x * blockDim.x + threadIdx.x) >> 6;
    const int nwaves = (gridDim.x * blockDim.x) >> 6;
    const int chunk = (E + nwaves - 1) / nwaves;
    const int e0 = gwave * chunk;
    const int e1 = (e0 + chunk < E) ? (e0 + chunk) : E;
    for (int e = e0; e < e1; ++e) {
        int s = src[e];
        int d = dst[e];
        int r = etype[e];
        float nm = edge_norm[e];
        const float* hb = Hb + (size_t)s * 256;
        const float* cf = w_comp + r * 4;
        float v = cf[0] * hb[lane] + cf[1] * hb[64 + lane] + cf[2] * hb[128 + lane] +
                  cf[3] * hb[192 + lane];
        atomicAdd(&out[(size_t)d * 64 + lane], v * nm);
    }
}

__global__ __launch_bounds__(256) void bias_relu_kernel(float* __restrict__ out,
                                                        const float* __restrict__ bias,
                                                        int total) {
    int i = blockIdx.x * blockDim.x + threadIdx.x;
    int stride = gridDim.x * blockDim.x;
    for (; i < total; i += stride) {
        float v = out[i] + bias[i & 63];
        out[i] = v > 0.f ? v : 0.f;
    }
}

// ============================ Launch ============================

extern "C" void kernel_launch(void* const* d_in, const int* in_sizes, int n_in,
                              void* d_out, int out_size, void* d_ws, size_t ws_size,
                              hipStream_t stream) {
    const float* h         = (const float*)d_in[0];
    const float* weight    = (const float*)d_in[1];
    const float* w_comp    = (const float*)d_in[2];
    const float* bias      = (const float*)d_in[3];
    const float* edge_norm = (const float*)d_in[4];
    const int*   src       = (const int*)d_in[5];
    const int*   dst       = (const int*)d_in[6];
    const int*   etype     = (const int*)d_in[7];
    float* out = (float*)d_out;

    const int N = in_sizes[0] / 64;
    const int E = in_sizes[4];
    const int nb = (N + 255) / 256;

    // workspace layout for the CSR path
    size_t gBytes      = (size_t)N * 256 * sizeof(float);   // G
    size_t packedBytes = (size_t)E * 16;                    // sorted edge records
    size_t intsBytes   = (size_t)(N + (N + 1) + N + nb) * sizeof(int);
    size_t need        = gBytes + packedBytes + intsBytes;

    if (ws_size >= need && nb <= 256) {
        char* p = (char*)d_ws;
        float* G       = (float*)p;                 p += gBytes;
        uint4* packed  = (uint4*)p;                 p += packedBytes;
        int* counts    = (int*)p;                   p += (size_t)N * sizeof(int);
        int* offsets   = (int*)p;                   p += (size_t)(N + 1) * sizeof(int);
        int* cursor    = (int*)p;                   p += (size_t)N * sizeof(int);
        int* bsum      = (int*)p;

        hipMemsetAsync(counts, 0, (size_t)N * sizeof(int), stream);
        hist_kernel<<<1024, 256, 0, stream>>>(dst, counts, E);
        scan1_kernel<<<nb, 256, 0, stream>>>(counts, bsum, N);
        scan2_kernel<<<1, 256, 0, stream>>>(bsum, nb, offsets, N, E);
        scan3_kernel<<<nb, 256, 0, stream>>>(counts, bsum, offsets, cursor, N);
        fill_kernel<<<1024, 256, 0, stream>>>(src, dst, etype, edge_norm, cursor, packed, E);
        agg_kernel<<<2048, 256, 0, stream>>>(packed, offsets, h, (const float4*)w_comp, G, N);
        transform_kernel<<<1024, 256, 0, stream>>>(G, weight, bias, out, N);
    } else if (ws_size >= gBytes) {
        float* Hb = (float*)d_ws;
        hipMemsetAsync(d_out, 0, (size_t)N * 64 * sizeof(float), stream);
        hb_kernel<<<1024, 256, 0, stream>>>(h, weight, Hb, N);
        edge_kernel<<<2048, 256, 0, stream>>>(Hb, w_comp, edge_norm, src, dst, etype, out, E);
        bias_relu_kernel<<<2048, 256, 0, stream>>>(out, bias, N * 64);
    }
}

// Round 3
// 213.890 us; speedup vs baseline: 1.1659x; 1.1244x over previous
//
#include <hip/hip_runtime.h>

// RGCN layer, basis decomposition — CSR-reordered formulation.
//
//   G[n][b][i] = sum_{e: dst[e]==n} (norm_e * w_comp[etype_e][b]) * h[src_e][i]
//   out[n][o]  = relu( sum_b sum_i G[n][b][i] * weight[b][i][o] + bias[o] )
//
// Pipeline: hist(dst) -> scan -> fill(sorted edge records) -> aggregate (no
// atomics on float data, 4-way software-pipelined gather) -> dense transform
// GEMM (fused bias+relu). Fallback to Hb+atomic path if ws too small.

constexpr int BASES = 4;

// ============================ CSR build ============================

__global__ __launch_bounds__(256) void hist_kernel(const int* __restrict__ dst,
                                                   int* __restrict__ counts, int E) {
    int i = blockIdx.x * blockDim.x + threadIdx.x;
    int st = gridDim.x * blockDim.x;
    for (; i < E; i += st) atomicAdd(&counts[dst[i]], 1);
}

// per-block sums of 256 counts
__global__ __launch_bounds__(256) void scan1_kernel(const int* __restrict__ counts,
                                                    int* __restrict__ bsum, int N) {
    __shared__ int s[256];
    int t = threadIdx.x;
    int i = blockIdx.x * 256 + t;
    s[t] = (i < N) ? counts[i] : 0;
    __syncthreads();
    for (int off = 128; off > 0; off >>= 1) {
        if (t < off) s[t] += s[t + off];
        __syncthreads();
    }
    if (t == 0) bsum[blockIdx.x] = s[0];
}

// exclusive scan of block sums (nb <= 256); also writes offsets[N] = E
__global__ __launch_bounds__(256) void scan2_kernel(int* __restrict__ bsum, int nb,
                                                    int* __restrict__ offsets, int N, int E) {
    __shared__ int s[256];
    int t = threadIdx.x;
    int v = (t < nb) ? bsum[t] : 0;
    s[t] = v;
    __syncthreads();
    for (int off = 1; off < 256; off <<= 1) {
        int x = (t >= off) ? s[t - off] : 0;
        __syncthreads();
        s[t] += x;
        __syncthreads();
    }
    if (t < nb) bsum[t] = s[t] - v;   // exclusive
    if (t == 0) offsets[N] = E;
}

// per-block exclusive scan + block offset -> offsets & cursor copy
__global__ __launch_bounds__(256) void scan3_kernel(const int* __restrict__ counts,
                                                    const int* __restrict__ bsum,
                                                    int* __restrict__ offsets,
                                                    int* __restrict__ cursor, int N) {
    __shared__ int s[256];
    int t = threadIdx.x;
    int i = blockIdx.x * 256 + t;
    int v = (i < N) ? counts[i] : 0;
    s[t] = v;
    __syncthreads();
    for (int off = 1; off < 256; off <<= 1) {
        int x = (t >= off) ? s[t - off] : 0;
        __syncthreads();
        s[t] += x;
        __syncthreads();
    }
    if (i < N) {
        int ex = s[t] - v + bsum[blockIdx.x];
        offsets[i] = ex;
        cursor[i] = ex;
    }
}

// scatter edges into dst-sorted order as packed 16B records {src, etype, norm, pad}
__global__ __launch_bounds__(256) void fill_kernel(const int* __restrict__ src,
                                                   const int* __restrict__ dst,
                                                   const int* __restrict__ etype,
                                                   const float* __restrict__ norm,
                                                   int* __restrict__ cursor,
                                                   uint4* __restrict__ packed, int E) {
    int i = blockIdx.x * blockDim.x + threadIdx.x;
    int st = gridDim.x * blockDim.x;
    for (; i < E; i += st) {
        int d = dst[i];
        int pos = atomicAdd(&cursor[d], 1);
        uint4 r;
        r.x = (unsigned)src[i];
        r.y = (unsigned)etype[i];
        r.z = __float_as_uint(norm[i]);
        r.w = 0u;
        packed[pos] = r;
    }
}

// ============================ Aggregation ============================
// One wave per node (lane = feature i). G accumulated in 4 VGPRs, no atomics.
// 4-way unrolled: all four records / coefficient rows / h rows issued as
// independent loads before any use, so 4 gather latencies overlap.
__global__ __launch_bounds__(256) void agg_kernel(const uint4* __restrict__ packed,
                                                  const int* __restrict__ offsets,
                                                  const float* __restrict__ h,
                                                  const float4* __restrict__ wc4,
                                                  float* __restrict__ G, int N) {
    const int lane = threadIdx.x & 63;
    int wave = (blockIdx.x * blockDim.x + threadIdx.x) >> 6;
    int nw = (gridDim.x * blockDim.x) >> 6;
    for (int n = wave; n < N; n += nw) {
        int e0 = offsets[n], e1 = offsets[n + 1];
        float g0 = 0.f, g1 = 0.f, g2 = 0.f, g3 = 0.f;
        int e = e0;
        for (; e + 4 <= e1; e += 4) {
            uint4 r0 = packed[e];
            uint4 r1 = packed[e + 1];
            uint4 r2 = packed[e + 2];
            uint4 r3 = packed[e + 3];
            float hv0 = h[(size_t)r0.x * 64 + lane];
            float hv1 = h[(size_t)r1.x * 64 + lane];
            float hv2 = h[(size_t)r2.x * 64 + lane];
            float hv3 = h[(size_t)r3.x * 64 + lane];
            float4 c0 = wc4[r0.y];
            float4 c1 = wc4[r1.y];
            float4 c2 = wc4[r2.y];
            float4 c3 = wc4[r3.y];
            float n0 = __uint_as_float(r0.z);
            float n1 = __uint_as_float(r1.z);
            float n2 = __uint_as_float(r2.z);
            float n3 = __uint_as_float(r3.z);
            float a0 = n0 * hv0, a1 = n1 * hv1, a2 = n2 * hv2, a3 = n3 * hv3;
            g0 = fmaf(c0.x, a0, g0); g1 = fmaf(c0.y, a0, g1);
            g2 = fmaf(c0.z, a0, g2); g3 = fmaf(c0.w, a0, g3);
            g0 = fmaf(c1.x, a1, g0); g1 = fmaf(c1.y, a1, g1);
            g2 = fmaf(c1.z, a1, g2); g3 = fmaf(c1.w, a1, g3);
            g0 = fmaf(c2.x, a2, g0); g1 = fmaf(c2.y, a2, g1);
            g2 = fmaf(c2.z, a2, g2); g3 = fmaf(c2.w, a2, g3);
            g0 = fmaf(c3.x, a3, g0); g1 = fmaf(c3.y, a3, g1);
            g2 = fmaf(c3.z, a3, g2); g3 = fmaf(c3.w, a3, g3);
        }
        for (; e < e1; ++e) {
            uint4 rec = packed[e];
            float hv = h[(size_t)rec.x * 64 + lane];
            float4 c = wc4[rec.y];
            float a = __uint_as_float(rec.z) * hv;
            g0 = fmaf(c.x, a, g0);
            g1 = fmaf(c.y, a, g1);
            g2 = fmaf(c.z, a, g2);
            g3 = fmaf(c.w, a, g3);
        }
        float* gp = G + (size_t)n * 256;
        gp[lane] = g0;
        gp[64 + lane] = g1;
        gp[128 + lane] = g2;
        gp[192 + lane] = g3;
    }
}

// ============================ Transform GEMM ============================
// out[n][o] = relu(bias[o] + sum_b sum_i G[n][b][i]*weight[b][i][o])
// Thread t: b = t>>6, o = t&63; weight column in 64 VGPRs. 16-node tiles
// staged through LDS; 4-way basis partials reduced via a second LDS buffer.
__global__ __launch_bounds__(256) void transform_kernel(const float* __restrict__ G,
                                                        const float* __restrict__ weight,
                                                        const float* __restrict__ bias,
                                                        float* __restrict__ out, int N) {
    __shared__ float sh[16 * 256];
    __shared__ float sp[16 * 256];
    const int t = threadIdx.x;
    const int b = t >> 6, o = t & 63;

    float wcol[64];
#pragma unroll
    for (int i = 0; i < 64; ++i) wcol[i] = weight[b * 4096 + i * 64 + o];
    const float bo = bias[o];

    const int ntiles = (N + 15) / 16;
    for (int tile = blockIdx.x; tile < ntiles; tile += gridDim.x) {
        const int n0 = tile * 16;
#pragma unroll
        for (int p = 0; p < 4; ++p) {                   // load 16x256 floats as float4
            int idx = p * 256 + t;                      // 0..1023 float4 slots
            int row = idx >> 6, col = idx & 63;
            int n = n0 + row;
            float4 v = (n < N) ? ((const float4*)G)[(size_t)n * 64 + col]
                               : make_float4(0.f, 0.f, 0.f, 0.f);
            ((float4*)sh)[idx] = v;
        }
        __syncthreads();
        for (int r = 0; r < 16; ++r) {
            const float* g = &sh[r * 256 + b * 64];     // wave-uniform -> broadcast
            float acc = 0.f;
#pragma unroll
            for (int i = 0; i < 64; i += 4) {
                float4 gv = *(const float4*)&g[i];
                acc = fmaf(gv.x, wcol[i], acc);
                acc = fmaf(gv.y, wcol[i + 1], acc);
                acc = fmaf(gv.z, wcol[i + 2], acc);
                acc = fmaf(gv.w, wcol[i + 3], acc);
            }
            sp[r * 256 + b * 64 + o] = acc;
        }
        __syncthreads();
#pragma unroll
        for (int p = 0; p < 4; ++p) {                   // reduce 4 basis partials
            int j = p * 256 + t;
            int r = j >> 6, oo = j & 63;
            int n = n0 + r;
            if (n < N) {
                float v = sp[r * 256 + oo] + sp[r * 256 + 64 + oo] +
                          sp[r * 256 + 128 + oo] + sp[r * 256 + 192 + oo] + bo;
                out[(size_t)n * 64 + oo] = v > 0.f ? v : 0.f;
            }
        }
        __syncthreads();
    }
}

// ============================ Fallback path (round-1) ============================

__global__ __launch_bounds__(256) void hb_kernel(const float* __restrict__ h,
                                                 const float* __restrict__ weight,
                                                 float* __restrict__ Hb, int N) {
    __shared__ float sh[16][64];
    const int t = threadIdx.x;
    const int b = t >> 6;
    const int o = t & 63;
    float wcol[64];
#pragma unroll
    for (int i = 0; i < 64; ++i) wcol[i] = weight[b * 4096 + i * 64 + o];
    for (int node0 = blockIdx.x * 16; node0 < N; node0 += gridDim.x * 16) {
        __syncthreads();
#pragma unroll
        for (int p = 0; p < 4; ++p) {
            int idx = p * 256 + t;
            int r = idx >> 6, c = idx & 63;
            int node = node0 + r;
            sh[r][c] = (node < N) ? h[(size_t)node * 64 + c] : 0.f;
        }
        __syncthreads();
        int rmax = (N - node0 < 16) ? (N - node0) : 16;
        for (int r = 0; r < rmax; ++r) {
            float acc = 0.f;
#pragma unroll
            for (int i = 0; i < 64; ++i) acc += sh[r][i] * wcol[i];
            Hb[(size_t)(node0 + r) * 256 + t] = acc;
        }
    }
}

__global__ __launch_bounds__(256) void edge_kernel(const float* __restrict__ Hb,
                                                   const float* __restrict__ w_comp,
                                                   const float* __restrict__ edge_norm,
                                                   const int* __restrict__ src,
                                                   const int* __restrict__ dst,
                                                   const int* __restrict__ etype,
                                                   float* __restrict__ out, int E) {
    const int lane = threadIdx.x & 63;
    const int gwave = (blockIdx.x * blockDim.x + threadIdx.x) >> 6;
    const int nwaves = (gridDim.x * blockDim.x) >> 6;
    const int chunk = (E + nwaves - 1) / nwaves;
    const int e0 = gwave * chunk;
    const int e1 = (e0 + chunk < E) ? (e0 + chunk) : E;
    for (int e = e0; e < e1; ++e) {
        int s = src[e];
        int d = dst[e];
        int r = etype[e];
        float nm = edge_norm[e];
        const float* hb = Hb + (size_t)s * 256;
        const float* cf = w_comp + r * 4;
        float v = cf[0] * hb[lane] + cf[1] * hb[64 + lane] + cf[2] * hb[128 + lane] +
                  cf[3] * hb[192 + lane];
        atomicAdd(&out[(size_t)d * 64 + lane], v * nm);
    }
}

__global__ __launch_bounds__(256) void bias_relu_kernel(float* __restrict__ out,
                                                        const float* __restrict__ bias,
                                                        int total) {
    int i = blockIdx.x * blockDim.x + threadIdx.x;
    int stride = gridDim.x * blockDim.x;
    for (; i < total; i += stride) {
        float v = out[i] + bias[i & 63];
        out[i] = v > 0.f ? v : 0.f;
    }
}

// ============================ Launch ============================

extern "C" void kernel_launch(void* const* d_in, const int* in_sizes, int n_in,
                              void* d_out, int out_size, void* d_ws, size_t ws_size,
                              hipStream_t stream) {
    const float* h         = (const float*)d_in[0];
    const float* weight    = (const float*)d_in[1];
    const float* w_comp    = (const float*)d_in[2];
    const float* bias      = (const float*)d_in[3];
    const float* edge_norm = (const float*)d_in[4];
    const int*   src       = (const int*)d_in[5];
    const int*   dst       = (const int*)d_in[6];
    const int*   etype     = (const int*)d_in[7];
    float* out = (float*)d_out;

    const int N = in_sizes[0] / 64;
    const int E = in_sizes[4];
    const int nb = (N + 255) / 256;

    // workspace layout for the CSR path
    size_t gBytes      = (size_t)N * 256 * sizeof(float);   // G
    size_t packedBytes = (size_t)E * 16;                    // sorted edge records
    size_t intsBytes   = (size_t)(N + (N + 1) + N + nb) * sizeof(int);
    size_t need        = gBytes + packedBytes + intsBytes;

    if (ws_size >= need && nb <= 256) {
        char* p = (char*)d_ws;
        float* G       = (float*)p;                 p += gBytes;
        uint4* packed  = (uint4*)p;                 p += packedBytes;
        int* counts    = (int*)p;                   p += (size_t)N * sizeof(int);
        int* offsets   = (int*)p;                   p += (size_t)(N + 1) * sizeof(int);
        int* cursor    = (int*)p;                   p += (size_t)N * sizeof(int);
        int* bsum      = (int*)p;

        hipMemsetAsync(counts, 0, (size_t)N * sizeof(int), stream);
        hist_kernel<<<1024, 256, 0, stream>>>(dst, counts, E);
        scan1_kernel<<<nb, 256, 0, stream>>>(counts, bsum, N);
        scan2_kernel<<<1, 256, 0, stream>>>(bsum, nb, offsets, N, E);
        scan3_kernel<<<nb, 256, 0, stream>>>(counts, bsum, offsets, cursor, N);
        fill_kernel<<<1024, 256, 0, stream>>>(src, dst, etype, edge_norm, cursor, packed, E);
        agg_kernel<<<2048, 256, 0, stream>>>(packed, offsets, h, (const float4*)w_comp, G, N);
        transform_kernel<<<1024, 256, 0, stream>>>(G, weight, bias, out, N);
    } else if (ws_size >= gBytes) {
        float* Hb = (float*)d_ws;
        hipMemsetAsync(d_out, 0, (size_t)N * 64 * sizeof(float), stream);
        hb_kernel<<<1024, 256, 0, stream>>>(h, weight, Hb, N);
        edge_kernel<<<2048, 256, 0, stream>>>(Hb, w_comp, edge_norm, src, dst, etype, out, E);
        bias_relu_kernel<<<2048, 256, 0, stream>>>(out, bias, N * 64);
    }
}